// Round 8
// baseline (798.768 us; speedup 1.0000x reference)
//
#include <hip/hip_runtime.h>

typedef __bf16 bf16;
typedef __bf16 bf16x8 __attribute__((ext_vector_type(8)));
typedef __bf16 bf16x4 __attribute__((ext_vector_type(4)));
typedef float f32x4 __attribute__((ext_vector_type(4)));

#define MFMA_BF16(A, B, C) __builtin_amdgcn_mfma_f32_16x16x32_bf16((A), (B), (C), 0, 0, 0)

#define EMB 1024
#define ODIM 2048
#define SEQ 2048
#define HEADS 16
#define HD 128

__device__ __forceinline__ void gload16(const bf16* g, const bf16* l) {
  __builtin_amdgcn_global_load_lds(
      (const __attribute__((address_space(1))) unsigned int*)(const void*)g,
      (__attribute__((address_space(3))) unsigned int*)(void*)l, 16, 0, 0);
}

// ---------------- prepass: f32 -> bf16 for q,k,v (3x4096x1024) and Wq,Wk,Wv (3x2048x1024) ----------------
__global__ __launch_bounds__(256) void cvt_bf16_k(const float* __restrict__ q,
                                                  const float* __restrict__ k,
                                                  const float* __restrict__ v,
                                                  const float* __restrict__ Wq,
                                                  const float* __restrict__ Wk,
                                                  const float* __restrict__ Wv,
                                                  bf16* __restrict__ Xall,
                                                  bf16* __restrict__ Wall) {
  const unsigned XV = 4096u * 1024u / 8u;
  const unsigned WV = 2048u * 1024u / 8u;
  unsigned id = blockIdx.x * 256 + threadIdx.x;
  const float* src;
  bf16* dst;
  size_t off;
  if (id < 3 * XV) {
    unsigned p = id / XV;
    off = (size_t)(id - p * XV) * 8;
    src = (p == 0) ? q : (p == 1 ? k : v);
    dst = Xall + (size_t)p * (4096u * 1024u);
  } else {
    unsigned id2 = id - 3 * XV;
    unsigned p = id2 / WV;
    off = (size_t)(id2 - p * WV) * 8;
    src = (p == 0) ? Wq : (p == 1 ? Wk : Wv);
    dst = Wall + (size_t)p * (2048u * 1024u);
  }
  float4 a = *(const float4*)(src + off);
  float4 b = *(const float4*)(src + off + 4);
  bf16x8 o;
  o[0] = (bf16)a.x; o[1] = (bf16)a.y; o[2] = (bf16)a.z; o[3] = (bf16)a.w;
  o[4] = (bf16)b.x; o[5] = (bf16)b.y; o[6] = (bf16)b.z; o[7] = (bf16)b.w;
  *(bf16x8*)(dst + off) = o;
}

// ---------------- mask bit-pack: mask (1,S,S) int32 -> mb[q][kt] uint64 ----------------
__global__ __launch_bounds__(256) void build_maskbits_k(const int* __restrict__ mask,
                                                        unsigned long long* __restrict__ mb) {
  int w = blockIdx.x * 256 + threadIdx.x;
  int q = w >> 5, c = w & 31;
  const int4* m4 = reinterpret_cast<const int4*>(mask + (size_t)q * SEQ + c * 64);
  unsigned long long bits = 0ull;
#pragma unroll
  for (int i = 0; i < 16; ++i) {
    int4 v = m4[i];
    if (v.x) bits |= 1ull << (i * 4 + 0);
    if (v.y) bits |= 1ull << (i * 4 + 1);
    if (v.z) bits |= 1ull << (i * 4 + 2);
    if (v.w) bits |= 1ull << (i * 4 + 3);
  }
  mb[w] = bits;
}

// ---------------- projection GEMMs (merged z=0,1,2): relu(X W^T + b)*oscale ----------------
__global__ __launch_bounds__(256) void proj_gemm_k(const bf16* __restrict__ Xall,
                                                   const bf16* __restrict__ Wall,
                                                   const float* __restrict__ bq,
                                                   const float* __restrict__ bk_,
                                                   const float* __restrict__ bv_,
                                                   bf16* __restrict__ Qb,
                                                   bf16* __restrict__ Kb,
                                                   bf16* __restrict__ Vt,
                                                   float qscale) {
  __shared__ union {
    struct { bf16 A[128 * 64]; bf16 B[128 * 64]; } s;
    bf16 C[128][136];
  } sm;

  const int t = threadIdx.x;
  const int lane = t & 63;
  const int wid = t >> 6;
  const int wm = wid >> 1, wn = wid & 1;
  const int lr = lane & 15, lg = lane >> 4;
  const int z = blockIdx.z;
  const int m0 = blockIdx.y * 128;
  const int n0 = blockIdx.x * 128;
  const bf16* X = Xall + (size_t)z * (4096u * 1024u);
  const bf16* W = Wall + (size_t)z * (2048u * 1024u);
  const float* bias = (z == 0) ? bq : (z == 1 ? bk_ : bv_);
  const float oscale = (z == 0) ? qscale : 1.0f;

  const int sr_ = t >> 3;
  const int scb = (t & 7) * 16;

  f32x4 acc[4][4];
#pragma unroll
  for (int i = 0; i < 4; ++i)
#pragma unroll
    for (int j = 0; j < 4; ++j) acc[i][j] = {0.f, 0.f, 0.f, 0.f};

  for (int k0 = 0; k0 < EMB; k0 += 64) {
#pragma unroll
    for (int j = 0; j < 4; ++j) {
      int r = j * 32 + sr_;
      int cb = scb ^ ((r & 7) << 4);
      gload16(X + (size_t)(m0 + r) * EMB + k0 + (cb >> 1), &sm.s.A[j * 2048 + t * 8]);
    }
#pragma unroll
    for (int j = 0; j < 4; ++j) {
      int r = j * 32 + sr_;
      int cb = scb ^ ((r & 7) << 4);
      gload16(W + (size_t)(n0 + r) * EMB + k0 + (cb >> 1), &sm.s.B[j * 2048 + t * 8]);
    }
    __syncthreads();

    bf16x8 af[4][2], bfr[4][2];
#pragma unroll
    for (int i = 0; i < 4; ++i)
#pragma unroll
      for (int s = 0; s < 2; ++s) {
        int ra = wm * 64 + i * 16 + lr;
        int ca = (s * 64 + lg * 16) ^ ((ra & 7) << 4);
        af[i][s] = *(const bf16x8*)&sm.s.A[ra * 64 + (ca >> 1)];
        int rb = wn * 64 + i * 16 + lr;
        int cb2 = (s * 64 + lg * 16) ^ ((rb & 7) << 4);
        bfr[i][s] = *(const bf16x8*)&sm.s.B[rb * 64 + (cb2 >> 1)];
      }
#pragma unroll
    for (int s = 0; s < 2; ++s)
#pragma unroll
      for (int mi = 0; mi < 4; ++mi)
#pragma unroll
        for (int ni = 0; ni < 4; ++ni)
          acc[mi][ni] = MFMA_BF16(af[mi][s], bfr[ni][s], acc[mi][ni]);
    __syncthreads();
  }

  float bv4[4];
#pragma unroll
  for (int ni = 0; ni < 4; ++ni) bv4[ni] = bias[n0 + wn * 64 + ni * 16 + lr];

  if (z < 2) {
    bf16* outN = (z == 0) ? Qb : Kb;
#pragma unroll
    for (int mi = 0; mi < 4; ++mi)
#pragma unroll
      for (int ni = 0; ni < 4; ++ni)
#pragma unroll
        for (int j = 0; j < 4; ++j) {
          float v = fmaxf(acc[mi][ni][j] + bv4[ni], 0.f) * oscale;
          int row = m0 + wm * 64 + mi * 16 + lg * 4 + j;
          int col = n0 + wn * 64 + ni * 16 + lr;
          outN[(size_t)row * ODIM + col] = (bf16)v;
        }
  } else {
#pragma unroll
    for (int mi = 0; mi < 4; ++mi)
#pragma unroll
      for (int ni = 0; ni < 4; ++ni)
#pragma unroll
        for (int j = 0; j < 4; ++j) {
          float v = fmaxf(acc[mi][ni][j] + bv4[ni], 0.f);
          int rit = wm * 64 + mi * 16 + lg * 4 + j;
          int cit = wn * 64 + ni * 16 + lr;
          sm.C[cit][rit] = (bf16)v;
        }
    __syncthreads();
    const int n = m0 >> 11;
    const int s0 = m0 & (SEQ - 1);
    const int h = blockIdx.x;
    bf16* base = Vt + ((size_t)(n * HEADS + h) * HD) * SEQ + s0;
#pragma unroll
    for (int i = 0; i < 8; ++i) {
      int cid = i * 256 + t;
      int d = cid >> 4, c = cid & 15;
      *(bf16x8*)(base + (size_t)d * SEQ + c * 8) = *(const bf16x8*)&sm.C[d][c * 8];
    }
  }
}

// ---------------- flash attention v8: single-buffered K/V, 68 KB LDS -> 2 blocks/CU (4 waves/SIMD) ----------------
// 256 blocks, 512 threads = 8 waves, 32 q-rows/wave. Same register body as round 6 (fits 128 VGPR).
// TLP (2 resident blocks) hides the QK->softmax->PV chain instead of register-hungry ILP.

__device__ __forceinline__ int kswz(int r, int c) {  // bf16 idx into Ks [64][128]
  int b = (r << 8) | (c << 1);
  b ^= (r & 7) << 4;
  return b >> 1;
}
__device__ __forceinline__ int vswz(int d, int s) {  // bf16 idx into Vs [128][64]
  int b = (d << 7) | (s << 1);
  b ^= (d & 7) << 4;
  return b >> 1;
}

__global__ __launch_bounds__(512, 4) void attn_k(const bf16* __restrict__ Qb,
                                                 const bf16* __restrict__ Kb,
                                                 const bf16* __restrict__ Vt,
                                                 const unsigned long long* __restrict__ mb,
                                                 float* __restrict__ out) {
  __shared__ bf16 Ks[64 * 128];   // 16 KB
  __shared__ bf16 Vs[128 * 64];   // 16 KB
  __shared__ bf16 Ps[8][32][72];  // 36 KB

  const int tid = threadIdx.x;
  const int lane = tid & 63;
  const int w = tid >> 6;
  const int lr = lane & 15, lg = lane >> 4;

  const int bid = blockIdx.x;
  const int swz = (bid & 7) * 32 + (bid >> 3);  // bijective: 256 = 8*32
  const int nh = swz >> 3;
  const int qt = swz & 7;
  const int n = nh >> 4, h = nh & 15;
  const int qrow = qt * 256 + w * 32;

  // Q fragments (B-operand: col=q=lane&15, k=d). Q pre-scaled by (1/sqrt(HD))*log2(e).
  bf16x8 qf[2][4];
#pragma unroll
  for (int g = 0; g < 2; ++g) {
    const bf16* qp = Qb + (size_t)(n * SEQ + qrow + g * 16 + lr) * ODIM + h * HD + lg * 8;
#pragma unroll
    for (int ks = 0; ks < 4; ++ks) qf[g][ks] = *(const bf16x8*)(qp + ks * 32);
  }

  // ones A-fragment: row 0 = 1.0 -> l = sum_k P[k][q]
  bf16x8 onesA;
  {
    bf16 o1 = (bf16)((lr == 0) ? 1.0f : 0.0f);
#pragma unroll
    for (int j = 0; j < 8; ++j) onesA[j] = o1;
  }

  const bf16* Kg = Kb + (size_t)(n * SEQ) * ODIM + h * HD;
  const bf16* Vg = Vt + (size_t)nh * HD * SEQ;

  // staging (512 threads): K 64x128 and V^T 128x64 -> 2 x bf16x8 per thread each
  const int rK = tid >> 4, cK = tid & 15;
  const int dV = tid >> 3, cV = tid & 7;
  const bf16* kgp = Kg + (size_t)rK * ODIM + cK * 8;
  const bf16* vgp = Vg + (size_t)dV * SEQ + cV * 8;

  bf16x8 kreg[2], vreg[2];
#pragma unroll
  for (int i = 0; i < 2; ++i) kreg[i] = *(const bf16x8*)(kgp + (size_t)i * 32 * ODIM);
#pragma unroll
  for (int i = 0; i < 2; ++i) vreg[i] = *(const bf16x8*)(vgp + (size_t)i * 64 * SEQ);
#pragma unroll
  for (int i = 0; i < 2; ++i) *(bf16x8*)&Ks[kswz(rK + i * 32, cK * 8)] = kreg[i];
#pragma unroll
  for (int i = 0; i < 2; ++i) *(bf16x8*)&Vs[vswz(dV + i * 64, cV * 8)] = vreg[i];
  __syncthreads();

  f32x4 oacc[2][9];  // [g][0..7]=O^T frags; [g][8]=l accumulator
#pragma unroll
  for (int g = 0; g < 2; ++g)
#pragma unroll
    for (int i = 0; i < 9; ++i) oacc[g][i] = {0.f, 0.f, 0.f, 0.f};
  float mrun[2] = {-3.0e38f, -3.0e38f};

  const int NT = SEQ / 64;
  for (int kt = 0; kt < NT; ++kt) {
    // ---- issue tile kt+1 global loads (latency hides under QK+softmax+PV) ----
    if (kt + 1 < NT) {
      const bf16* kn = kgp + (size_t)(kt + 1) * 64 * ODIM;
      const bf16* vn = vgp + (size_t)(kt + 1) * 64;
#pragma unroll
      for (int i = 0; i < 2; ++i) kreg[i] = *(const bf16x8*)(kn + (size_t)i * 32 * ODIM);
#pragma unroll
      for (int i = 0; i < 2; ++i) vreg[i] = *(const bf16x8*)(vn + (size_t)i * 64 * SEQ);
    }

    unsigned long long mw0 = mb[(size_t)(qrow + lr) * 32 + kt];
    unsigned long long mw1 = mb[(size_t)(qrow + 16 + lr) * 32 + kt];

    // ---- mask-as-accumulator-init, then S^T = K Q^T ----
    f32x4 sacc[2][4];
#pragma unroll
    for (int f = 0; f < 4; ++f)
#pragma unroll
      for (int j = 0; j < 4; ++j) {
        int kk = f * 16 + lg * 4 + j;
        sacc[0][f][j] = ((mw0 >> kk) & 1ull) ? 0.f : -1.0e7f;
        sacc[1][f][j] = ((mw1 >> kk) & 1ull) ? 0.f : -1.0e7f;
      }
    __builtin_amdgcn_s_setprio(1);
#pragma unroll
    for (int f = 0; f < 4; ++f) {
#pragma unroll
      for (int ks = 0; ks < 4; ++ks) {
        bf16x8 kf = *(const bf16x8*)&Ks[kswz(f * 16 + lr, ks * 32 + lg * 8)];
        sacc[0][f] = MFMA_BF16(kf, qf[0][ks], sacc[0][f]);
        sacc[1][f] = MFMA_BF16(kf, qf[1][ks], sacc[1][f]);
      }
    }
    __builtin_amdgcn_s_setprio(0);

    // ---- lane-local online softmax (log2 domain) ----
    float mt[2] = {-3.0e38f, -3.0e38f};
#pragma unroll
    for (int g = 0; g < 2; ++g) {
#pragma unroll
      for (int f = 0; f < 4; ++f) {
        float a = fmaxf(sacc[g][f][0], sacc[g][f][1]);
        float b = fmaxf(sacc[g][f][2], sacc[g][f][3]);
        mt[g] = fmaxf(mt[g], fmaxf(a, b));
      }
      mt[g] = fmaxf(mt[g], __shfl_xor(mt[g], 16));
      mt[g] = fmaxf(mt[g], __shfl_xor(mt[g], 32));
    }

    // defer-max (T13): rescale only when max moved by >8 (log2 units; P <= 256)
    if (!__all((mt[0] <= mrun[0] + 8.0f) && (mt[1] <= mrun[1] + 8.0f))) {
#pragma unroll
      for (int g = 0; g < 2; ++g) {
        float mnew = fmaxf(mrun[g], mt[g]);
        float alpha = exp2f(mrun[g] - mnew);
        mrun[g] = mnew;
#pragma unroll
        for (int df = 0; df < 9; ++df)
#pragma unroll
          for (int j = 0; j < 4; ++j) oacc[g][df][j] *= alpha;
      }
    }

    // ---- P = exp2(S - m) -> per-wave LDS ----
#pragma unroll
    for (int g = 0; g < 2; ++g)
#pragma unroll
      for (int f = 0; f < 4; ++f) {
        bf16x4 pw;
#pragma unroll
        for (int j = 0; j < 4; ++j) pw[j] = (bf16)exp2f(sacc[g][f][j] - mrun[g]);
        *(bf16x4*)&Ps[w][g * 16 + lr][f * 16 + lg * 4] = pw;
      }

    bf16x8 pB[2][2];
#pragma unroll
    for (int g = 0; g < 2; ++g)
#pragma unroll
      for (int ks = 0; ks < 2; ++ks)
        pB[g][ks] = *(const bf16x8*)&Ps[w][g * 16 + lr][ks * 32 + lg * 8];

    // ---- O^T += V^T P; df=8 (l) via register ones fragment ----
    __builtin_amdgcn_s_setprio(1);
#pragma unroll
    for (int df = 0; df < 8; ++df) {
#pragma unroll
      for (int ks = 0; ks < 2; ++ks) {
        bf16x8 vf = *(const bf16x8*)&Vs[vswz(df * 16 + lr, ks * 32 + lg * 8)];
        oacc[0][df] = MFMA_BF16(vf, pB[0][ks], oacc[0][df]);
        oacc[1][df] = MFMA_BF16(vf, pB[1][ks], oacc[1][df]);
      }
    }
#pragma unroll
    for (int ks = 0; ks < 2; ++ks) {
      oacc[0][8] = MFMA_BF16(onesA, pB[0][ks], oacc[0][8]);
      oacc[1][8] = MFMA_BF16(onesA, pB[1][ks], oacc[1][8]);
    }
    __builtin_amdgcn_s_setprio(0);

    // ---- rotate the single K/V buffers ----
    if (kt + 1 < NT) {
      __syncthreads();  // all waves done reading Ks/Vs for tile kt
#pragma unroll
      for (int i = 0; i < 2; ++i) *(bf16x8*)&Ks[kswz(rK + i * 32, cK * 8)] = kreg[i];
#pragma unroll
      for (int i = 0; i < 2; ++i) *(bf16x8*)&Vs[vswz(dV + i * 64, cV * 8)] = vreg[i];
      __syncthreads();  // tile kt+1 staged
    }
  }

  // ---- epilogue: l at (lg=0, j=0, col=lr); O /= l; float4 stores ----
#pragma unroll
  for (int g = 0; g < 2; ++g) {
    float l = __shfl(oacc[g][8][0], lr);
    float inv = 1.0f / l;
    float* obase = out + (size_t)(n * SEQ + qrow + g * 16 + lr) * ODIM + h * HD;
#pragma unroll
    for (int df = 0; df < 8; ++df) {
      f32x4 o;
#pragma unroll
      for (int j = 0; j < 4; ++j) o[j] = oacc[g][df][j] * inv;
      *(f32x4*)(obase + df * 16 + lg * 4) = o;
    }
  }
}

extern "C" void kernel_launch(void* const* d_in, const int* in_sizes, int n_in,
                              void* d_out, int out_size, void* d_ws, size_t ws_size,
                              hipStream_t stream) {
  const float* q   = (const float*)d_in[0];
  const float* k   = (const float*)d_in[1];
  const float* v   = (const float*)d_in[2];
  const int*  mask = (const int*)d_in[3];
  const float* Wq  = (const float*)d_in[4];
  const float* bq  = (const float*)d_in[5];
  const float* Wk  = (const float*)d_in[6];
  const float* bk  = (const float*)d_in[7];
  const float* Wv  = (const float*)d_in[8];
  const float* bv  = (const float*)d_in[9];
  float* out = (float*)d_out;

  char* ws = (char*)d_ws;
  const size_t PLANE = (size_t)4096 * 2048 * sizeof(bf16);  // 16 MiB
  bf16* Qb = (bf16*)ws;
  bf16* Kb = (bf16*)(ws + PLANE);
  bf16* Vt = (bf16*)(ws + 2 * PLANE);
  unsigned long long* mb = (unsigned long long*)(ws + 3 * PLANE);            // 4 MiB
  bf16* Xall = (bf16*)(ws + 3 * PLANE + (4u << 20));                         // 24 MiB
  bf16* Wall = (bf16*)(ws + 3 * PLANE + (4u << 20) + (size_t)3 * 4096 * 1024 * 2);  // 12 MiB

  // 1/sqrt(128) * log2(e): softmax runs in exp2 domain
  const float qscale = 0.08838834764831845f * 1.4426950408889634f;

  cvt_bf16_k<<<9216, 256, 0, stream>>>(q, k, v, Wq, Wk, Wv, Xall, Wall);
  build_maskbits_k<<<256, 256, 0, stream>>>(mask, mb);
  proj_gemm_k<<<dim3(16, 32, 3), 256, 0, stream>>>(Xall, Wall, bq, bk, bv, Qb, Kb, Vt, qscale);
  attn_k<<<256, 512, 0, stream>>>(Qb, Kb, Vt, mb, out);
}

// Round 9
// 199.843 us; speedup vs baseline: 3.9970x; 3.9970x over previous
//
#include <hip/hip_runtime.h>

typedef __bf16 bf16;
typedef __bf16 bf16x8 __attribute__((ext_vector_type(8)));
typedef __bf16 bf16x4 __attribute__((ext_vector_type(4)));
typedef float f32x4 __attribute__((ext_vector_type(4)));

#define MFMA_BF16(A, B, C) __builtin_amdgcn_mfma_f32_16x16x32_bf16((A), (B), (C), 0, 0, 0)

#define EMB 1024
#define ODIM 2048
#define SEQ 2048
#define HEADS 16
#define HD 128

__device__ __forceinline__ void gload16(const bf16* g, const bf16* l) {
  __builtin_amdgcn_global_load_lds(
      (const __attribute__((address_space(1))) unsigned int*)(const void*)g,
      (__attribute__((address_space(3))) unsigned int*)(void*)l, 16, 0, 0);
}

// ---------------- prepass: f32 -> bf16 for q,k,v (3x4096x1024) and Wq,Wk,Wv (3x2048x1024) ----------------
__global__ __launch_bounds__(256) void cvt_bf16_k(const float* __restrict__ q,
                                                  const float* __restrict__ k,
                                                  const float* __restrict__ v,
                                                  const float* __restrict__ Wq,
                                                  const float* __restrict__ Wk,
                                                  const float* __restrict__ Wv,
                                                  bf16* __restrict__ Xall,
                                                  bf16* __restrict__ Wall) {
  const unsigned XV = 4096u * 1024u / 8u;
  const unsigned WV = 2048u * 1024u / 8u;
  unsigned id = blockIdx.x * 256 + threadIdx.x;
  const float* src;
  bf16* dst;
  size_t off;
  if (id < 3 * XV) {
    unsigned p = id / XV;
    off = (size_t)(id - p * XV) * 8;
    src = (p == 0) ? q : (p == 1 ? k : v);
    dst = Xall + (size_t)p * (4096u * 1024u);
  } else {
    unsigned id2 = id - 3 * XV;
    unsigned p = id2 / WV;
    off = (size_t)(id2 - p * WV) * 8;
    src = (p == 0) ? Wq : (p == 1 ? Wk : Wv);
    dst = Wall + (size_t)p * (2048u * 1024u);
  }
  float4 a = *(const float4*)(src + off);
  float4 b = *(const float4*)(src + off + 4);
  bf16x8 o;
  o[0] = (bf16)a.x; o[1] = (bf16)a.y; o[2] = (bf16)a.z; o[3] = (bf16)a.w;
  o[4] = (bf16)b.x; o[5] = (bf16)b.y; o[6] = (bf16)b.z; o[7] = (bf16)b.w;
  *(bf16x8*)(dst + off) = o;
}

// ---------------- mask bit-pack: mask (1,S,S) int32 -> mb[q][kt] uint64 ----------------
__global__ __launch_bounds__(256) void build_maskbits_k(const int* __restrict__ mask,
                                                        unsigned long long* __restrict__ mb) {
  int w = blockIdx.x * 256 + threadIdx.x;
  int q = w >> 5, c = w & 31;
  const int4* m4 = reinterpret_cast<const int4*>(mask + (size_t)q * SEQ + c * 64);
  unsigned long long bits = 0ull;
#pragma unroll
  for (int i = 0; i < 16; ++i) {
    int4 v = m4[i];
    if (v.x) bits |= 1ull << (i * 4 + 0);
    if (v.y) bits |= 1ull << (i * 4 + 1);
    if (v.z) bits |= 1ull << (i * 4 + 2);
    if (v.w) bits |= 1ull << (i * 4 + 3);
  }
  mb[w] = bits;
}

// ---------------- projection GEMMs (merged z=0,1,2): relu(X W^T + b)*oscale ----------------
__global__ __launch_bounds__(256) void proj_gemm_k(const bf16* __restrict__ Xall,
                                                   const bf16* __restrict__ Wall,
                                                   const float* __restrict__ bq,
                                                   const float* __restrict__ bk_,
                                                   const float* __restrict__ bv_,
                                                   bf16* __restrict__ Qb,
                                                   bf16* __restrict__ Kb,
                                                   bf16* __restrict__ Vt,
                                                   float qscale) {
  __shared__ union {
    struct { bf16 A[128 * 64]; bf16 B[128 * 64]; } s;
    bf16 C[128][136];
  } sm;

  const int t = threadIdx.x;
  const int lane = t & 63;
  const int wid = t >> 6;
  const int wm = wid >> 1, wn = wid & 1;
  const int lr = lane & 15, lg = lane >> 4;
  const int z = blockIdx.z;
  const int m0 = blockIdx.y * 128;
  const int n0 = blockIdx.x * 128;
  const bf16* X = Xall + (size_t)z * (4096u * 1024u);
  const bf16* W = Wall + (size_t)z * (2048u * 1024u);
  const float* bias = (z == 0) ? bq : (z == 1 ? bk_ : bv_);
  const float oscale = (z == 0) ? qscale : 1.0f;

  const int sr_ = t >> 3;
  const int scb = (t & 7) * 16;

  f32x4 acc[4][4];
#pragma unroll
  for (int i = 0; i < 4; ++i)
#pragma unroll
    for (int j = 0; j < 4; ++j) acc[i][j] = {0.f, 0.f, 0.f, 0.f};

  for (int k0 = 0; k0 < EMB; k0 += 64) {
#pragma unroll
    for (int j = 0; j < 4; ++j) {
      int r = j * 32 + sr_;
      int cb = scb ^ ((r & 7) << 4);
      gload16(X + (size_t)(m0 + r) * EMB + k0 + (cb >> 1), &sm.s.A[j * 2048 + t * 8]);
    }
#pragma unroll
    for (int j = 0; j < 4; ++j) {
      int r = j * 32 + sr_;
      int cb = scb ^ ((r & 7) << 4);
      gload16(W + (size_t)(n0 + r) * EMB + k0 + (cb >> 1), &sm.s.B[j * 2048 + t * 8]);
    }
    __syncthreads();

    bf16x8 af[4][2], bfr[4][2];
#pragma unroll
    for (int i = 0; i < 4; ++i)
#pragma unroll
      for (int s = 0; s < 2; ++s) {
        int ra = wm * 64 + i * 16 + lr;
        int ca = (s * 64 + lg * 16) ^ ((ra & 7) << 4);
        af[i][s] = *(const bf16x8*)&sm.s.A[ra * 64 + (ca >> 1)];
        int rb = wn * 64 + i * 16 + lr;
        int cb2 = (s * 64 + lg * 16) ^ ((rb & 7) << 4);
        bfr[i][s] = *(const bf16x8*)&sm.s.B[rb * 64 + (cb2 >> 1)];
      }
#pragma unroll
    for (int s = 0; s < 2; ++s)
#pragma unroll
      for (int mi = 0; mi < 4; ++mi)
#pragma unroll
        for (int ni = 0; ni < 4; ++ni)
          acc[mi][ni] = MFMA_BF16(af[mi][s], bfr[ni][s], acc[mi][ni]);
    __syncthreads();
  }

  float bv4[4];
#pragma unroll
  for (int ni = 0; ni < 4; ++ni) bv4[ni] = bias[n0 + wn * 64 + ni * 16 + lr];

  if (z < 2) {
    bf16* outN = (z == 0) ? Qb : Kb;
#pragma unroll
    for (int mi = 0; mi < 4; ++mi)
#pragma unroll
      for (int ni = 0; ni < 4; ++ni)
#pragma unroll
        for (int j = 0; j < 4; ++j) {
          float v = fmaxf(acc[mi][ni][j] + bv4[ni], 0.f) * oscale;
          int row = m0 + wm * 64 + mi * 16 + lg * 4 + j;
          int col = n0 + wn * 64 + ni * 16 + lr;
          outN[(size_t)row * ODIM + col] = (bf16)v;
        }
  } else {
#pragma unroll
    for (int mi = 0; mi < 4; ++mi)
#pragma unroll
      for (int ni = 0; ni < 4; ++ni)
#pragma unroll
        for (int j = 0; j < 4; ++j) {
          float v = fmaxf(acc[mi][ni][j] + bv4[ni], 0.f);
          int rit = wm * 64 + mi * 16 + lg * 4 + j;
          int cit = wn * 64 + ni * 16 + lr;
          sm.C[cit][rit] = (bf16)v;
        }
    __syncthreads();
    const int n = m0 >> 11;
    const int s0 = m0 & (SEQ - 1);
    const int h = blockIdx.x;
    bf16* base = Vt + ((size_t)(n * HEADS + h) * HD) * SEQ + s0;
#pragma unroll
    for (int i = 0; i < 8; ++i) {
      int cid = i * 256 + t;
      int d = cid >> 4, c = cid & 15;
      *(bf16x8*)(base + (size_t)d * SEQ + c * 8) = *(const bf16x8*)&sm.C[d][c * 8];
    }
  }
}

// ---------------- flash attention v9: round-8 structure, corrected launch_bounds ----------------
// 68 KB LDS + 128 VGPR -> 2 blocks/CU (16 waves/CU) by LDS AND register budget.
// __launch_bounds__ 2nd arg behaves CUDA-style here (min blocks/CU): (512,2) -> 128 VGPR cap.
// 256 blocks, 512 threads = 8 waves, 32 q-rows/wave; single-buffered K/V, 2 barriers/tile.

__device__ __forceinline__ int kswz(int r, int c) {  // bf16 idx into Ks [64][128]
  int b = (r << 8) | (c << 1);
  b ^= (r & 7) << 4;
  return b >> 1;
}
__device__ __forceinline__ int vswz(int d, int s) {  // bf16 idx into Vs [128][64]
  int b = (d << 7) | (s << 1);
  b ^= (d & 7) << 4;
  return b >> 1;
}

__global__ __launch_bounds__(512, 2) void attn_k(const bf16* __restrict__ Qb,
                                                 const bf16* __restrict__ Kb,
                                                 const bf16* __restrict__ Vt,
                                                 const unsigned long long* __restrict__ mb,
                                                 float* __restrict__ out) {
  __shared__ bf16 Ks[64 * 128];   // 16 KB
  __shared__ bf16 Vs[128 * 64];   // 16 KB
  __shared__ bf16 Ps[8][32][72];  // 36 KB

  const int tid = threadIdx.x;
  const int lane = tid & 63;
  const int w = tid >> 6;
  const int lr = lane & 15, lg = lane >> 4;

  const int bid = blockIdx.x;
  const int swz = (bid & 7) * 32 + (bid >> 3);  // bijective: 256 = 8*32
  const int nh = swz >> 3;
  const int qt = swz & 7;
  const int n = nh >> 4, h = nh & 15;
  const int qrow = qt * 256 + w * 32;

  // Q fragments (B-operand: col=q=lane&15, k=d). Q pre-scaled by (1/sqrt(HD))*log2(e).
  bf16x8 qf[2][4];
#pragma unroll
  for (int g = 0; g < 2; ++g) {
    const bf16* qp = Qb + (size_t)(n * SEQ + qrow + g * 16 + lr) * ODIM + h * HD + lg * 8;
#pragma unroll
    for (int ks = 0; ks < 4; ++ks) qf[g][ks] = *(const bf16x8*)(qp + ks * 32);
  }

  // ones A-fragment: row 0 = 1.0 -> l = sum_k P[k][q]
  bf16x8 onesA;
  {
    bf16 o1 = (bf16)((lr == 0) ? 1.0f : 0.0f);
#pragma unroll
    for (int j = 0; j < 8; ++j) onesA[j] = o1;
  }

  const bf16* Kg = Kb + (size_t)(n * SEQ) * ODIM + h * HD;
  const bf16* Vg = Vt + (size_t)nh * HD * SEQ;

  // staging (512 threads): K 64x128 and V^T 128x64 -> 2 x bf16x8 per thread each
  const int rK = tid >> 4, cK = tid & 15;
  const int dV = tid >> 3, cV = tid & 7;
  const bf16* kgp = Kg + (size_t)rK * ODIM + cK * 8;
  const bf16* vgp = Vg + (size_t)dV * SEQ + cV * 8;

  bf16x8 kreg[2], vreg[2];
#pragma unroll
  for (int i = 0; i < 2; ++i) kreg[i] = *(const bf16x8*)(kgp + (size_t)i * 32 * ODIM);
#pragma unroll
  for (int i = 0; i < 2; ++i) vreg[i] = *(const bf16x8*)(vgp + (size_t)i * 64 * SEQ);
#pragma unroll
  for (int i = 0; i < 2; ++i) *(bf16x8*)&Ks[kswz(rK + i * 32, cK * 8)] = kreg[i];
#pragma unroll
  for (int i = 0; i < 2; ++i) *(bf16x8*)&Vs[vswz(dV + i * 64, cV * 8)] = vreg[i];
  __syncthreads();

  f32x4 oacc[2][9];  // [g][0..7]=O^T frags; [g][8]=l accumulator
#pragma unroll
  for (int g = 0; g < 2; ++g)
#pragma unroll
    for (int i = 0; i < 9; ++i) oacc[g][i] = {0.f, 0.f, 0.f, 0.f};
  float mrun[2] = {-3.0e38f, -3.0e38f};

  const int NT = SEQ / 64;
  for (int kt = 0; kt < NT; ++kt) {
    // ---- issue tile kt+1 global loads (latency hides under QK+softmax+PV) ----
    if (kt + 1 < NT) {
      const bf16* kn = kgp + (size_t)(kt + 1) * 64 * ODIM;
      const bf16* vn = vgp + (size_t)(kt + 1) * 64;
#pragma unroll
      for (int i = 0; i < 2; ++i) kreg[i] = *(const bf16x8*)(kn + (size_t)i * 32 * ODIM);
#pragma unroll
      for (int i = 0; i < 2; ++i) vreg[i] = *(const bf16x8*)(vn + (size_t)i * 64 * SEQ);
    }

    unsigned long long mw0 = mb[(size_t)(qrow + lr) * 32 + kt];
    unsigned long long mw1 = mb[(size_t)(qrow + 16 + lr) * 32 + kt];

    // ---- mask-as-accumulator-init, then S^T = K Q^T ----
    f32x4 sacc[2][4];
#pragma unroll
    for (int f = 0; f < 4; ++f)
#pragma unroll
      for (int j = 0; j < 4; ++j) {
        int kk = f * 16 + lg * 4 + j;
        sacc[0][f][j] = ((mw0 >> kk) & 1ull) ? 0.f : -1.0e7f;
        sacc[1][f][j] = ((mw1 >> kk) & 1ull) ? 0.f : -1.0e7f;
      }
    __builtin_amdgcn_s_setprio(1);
#pragma unroll
    for (int f = 0; f < 4; ++f) {
#pragma unroll
      for (int ks = 0; ks < 4; ++ks) {
        bf16x8 kf = *(const bf16x8*)&Ks[kswz(f * 16 + lr, ks * 32 + lg * 8)];
        sacc[0][f] = MFMA_BF16(kf, qf[0][ks], sacc[0][f]);
        sacc[1][f] = MFMA_BF16(kf, qf[1][ks], sacc[1][f]);
      }
    }
    __builtin_amdgcn_s_setprio(0);

    // ---- lane-local online softmax (log2 domain) ----
    float mt[2] = {-3.0e38f, -3.0e38f};
#pragma unroll
    for (int g = 0; g < 2; ++g) {
#pragma unroll
      for (int f = 0; f < 4; ++f) {
        float a = fmaxf(sacc[g][f][0], sacc[g][f][1]);
        float b = fmaxf(sacc[g][f][2], sacc[g][f][3]);
        mt[g] = fmaxf(mt[g], fmaxf(a, b));
      }
      mt[g] = fmaxf(mt[g], __shfl_xor(mt[g], 16));
      mt[g] = fmaxf(mt[g], __shfl_xor(mt[g], 32));
    }

    // defer-max (T13): rescale only when max moved by >8 (log2 units; P <= 256)
    if (!__all((mt[0] <= mrun[0] + 8.0f) && (mt[1] <= mrun[1] + 8.0f))) {
#pragma unroll
      for (int g = 0; g < 2; ++g) {
        float mnew = fmaxf(mrun[g], mt[g]);
        float alpha = exp2f(mrun[g] - mnew);
        mrun[g] = mnew;
#pragma unroll
        for (int df = 0; df < 9; ++df)
#pragma unroll
          for (int j = 0; j < 4; ++j) oacc[g][df][j] *= alpha;
      }
    }

    // ---- P = exp2(S - m) -> per-wave LDS ----
#pragma unroll
    for (int g = 0; g < 2; ++g)
#pragma unroll
      for (int f = 0; f < 4; ++f) {
        bf16x4 pw;
#pragma unroll
        for (int j = 0; j < 4; ++j) pw[j] = (bf16)exp2f(sacc[g][f][j] - mrun[g]);
        *(bf16x4*)&Ps[w][g * 16 + lr][f * 16 + lg * 4] = pw;
      }

    bf16x8 pB[2][2];
#pragma unroll
    for (int g = 0; g < 2; ++g)
#pragma unroll
      for (int ks = 0; ks < 2; ++ks)
        pB[g][ks] = *(const bf16x8*)&Ps[w][g * 16 + lr][ks * 32 + lg * 8];

    // ---- O^T += V^T P; df=8 (l) via register ones fragment ----
    __builtin_amdgcn_s_setprio(1);
#pragma unroll
    for (int df = 0; df < 8; ++df) {
#pragma unroll
      for (int ks = 0; ks < 2; ++ks) {
        bf16x8 vf = *(const bf16x8*)&Vs[vswz(df * 16 + lr, ks * 32 + lg * 8)];
        oacc[0][df] = MFMA_BF16(vf, pB[0][ks], oacc[0][df]);
        oacc[1][df] = MFMA_BF16(vf, pB[1][ks], oacc[1][df]);
      }
    }
#pragma unroll
    for (int ks = 0; ks < 2; ++ks) {
      oacc[0][8] = MFMA_BF16(onesA, pB[0][ks], oacc[0][8]);
      oacc[1][8] = MFMA_BF16(onesA, pB[1][ks], oacc[1][8]);
    }
    __builtin_amdgcn_s_setprio(0);

    // ---- rotate the single K/V buffers ----
    if (kt + 1 < NT) {
      __syncthreads();  // all waves done reading Ks/Vs for tile kt
#pragma unroll
      for (int i = 0; i < 2; ++i) *(bf16x8*)&Ks[kswz(rK + i * 32, cK * 8)] = kreg[i];
#pragma unroll
      for (int i = 0; i < 2; ++i) *(bf16x8*)&Vs[vswz(dV + i * 64, cV * 8)] = vreg[i];
      __syncthreads();  // tile kt+1 staged
    }
  }

  // ---- epilogue: l at (lg=0, j=0, col=lr); O /= l; float4 stores ----
#pragma unroll
  for (int g = 0; g < 2; ++g) {
    float l = __shfl(oacc[g][8][0], lr);
    float inv = 1.0f / l;
    float* obase = out + (size_t)(n * SEQ + qrow + g * 16 + lr) * ODIM + h * HD;
#pragma unroll
    for (int df = 0; df < 8; ++df) {
      f32x4 o;
#pragma unroll
      for (int j = 0; j < 4; ++j) o[j] = oacc[g][df][j] * inv;
      *(f32x4*)(obase + df * 16 + lg * 4) = o;
    }
  }
}

extern "C" void kernel_launch(void* const* d_in, const int* in_sizes, int n_in,
                              void* d_out, int out_size, void* d_ws, size_t ws_size,
                              hipStream_t stream) {
  const float* q   = (const float*)d_in[0];
  const float* k   = (const float*)d_in[1];
  const float* v   = (const float*)d_in[2];
  const int*  mask = (const int*)d_in[3];
  const float* Wq  = (const float*)d_in[4];
  const float* bq  = (const float*)d_in[5];
  const float* Wk  = (const float*)d_in[6];
  const float* bk  = (const float*)d_in[7];
  const float* Wv  = (const float*)d_in[8];
  const float* bv  = (const float*)d_in[9];
  float* out = (float*)d_out;

  char* ws = (char*)d_ws;
  const size_t PLANE = (size_t)4096 * 2048 * sizeof(bf16);  // 16 MiB
  bf16* Qb = (bf16*)ws;
  bf16* Kb = (bf16*)(ws + PLANE);
  bf16* Vt = (bf16*)(ws + 2 * PLANE);
  unsigned long long* mb = (unsigned long long*)(ws + 3 * PLANE);            // 4 MiB
  bf16* Xall = (bf16*)(ws + 3 * PLANE + (4u << 20));                         // 24 MiB
  bf16* Wall = (bf16*)(ws + 3 * PLANE + (4u << 20) + (size_t)3 * 4096 * 1024 * 2);  // 12 MiB

  // 1/sqrt(128) * log2(e): softmax runs in exp2 domain
  const float qscale = 0.08838834764831845f * 1.4426950408889634f;

  cvt_bf16_k<<<9216, 256, 0, stream>>>(q, k, v, Wq, Wk, Wv, Xall, Wall);
  build_maskbits_k<<<256, 256, 0, stream>>>(mask, mb);
  proj_gemm_k<<<dim3(16, 32, 3), 256, 0, stream>>>(Xall, Wall, bq, bk, bv, Qb, Kb, Vt, qscale);
  attn_k<<<256, 512, 0, stream>>>(Qb, Kb, Vt, mb, out);
}